// Round 8
// baseline (31970.432 us; speedup 1.0000x reference)
//
#include <hip/hip_runtime.h>
#include <cstdint>
#include <cmath>

// Problem constants
constexpr int SEQ  = 2048;   // sequence length S
constexpr int EMB  = 512;    // embed dim E
constexpr int HID  = 256;    // per-direction hidden H
constexpr int GATE = 1024;   // 4*H
constexpr int NTAG = 32;     // tagset T
constexpr float FNEG = -10000.0f;

typedef _Float16 half2_t __attribute__((ext_vector_type(2)));

// v_dot2_f32_f16: fp32 += dot(2xfp16, 2xfp16). Full fp32 accumulate.
__device__ __forceinline__ float dot2(unsigned int a, unsigned int b,
                                      float c) {
#if defined(__has_builtin) && __has_builtin(__builtin_amdgcn_fdot2)
  return __builtin_amdgcn_fdot2(__builtin_bit_cast(half2_t, a),
                                __builtin_bit_cast(half2_t, b), c, false);
#else
  float r = c;
  asm("v_dot2_f32_f16 %0, %1, %2, %0" : "+v"(r) : "v"(a), "v"(b));
  return r;
#endif
}

// pack two fp32 -> one dword of two fp16 (RNE via scalar cvt)
__device__ __forceinline__ unsigned int packh2(float x, float y) {
  const unsigned short lo = __builtin_bit_cast(unsigned short, (_Float16)x);
  const unsigned short hi = __builtin_bit_cast(unsigned short, (_Float16)y);
  return (unsigned int)lo | ((unsigned int)hi << 16);
}

// ---------------------------------------------------------------------------
// Kernel 1: px[dir][s][j] = emb[t_eff(dir,s)] . w_ih_dir[j] + b_dir[j]
// Tiled fp32 GEMM (exact; all LSTM gate inputs carry full fp32 px).
// ---------------------------------------------------------------------------
__global__ __launch_bounds__(256) void px_gemm(
    const int* __restrict__ sent, const float* __restrict__ embed,
    const float* __restrict__ w_ih_f, const float* __restrict__ b_f,
    const float* __restrict__ w_ih_b, const float* __restrict__ b_b,
    float* __restrict__ px)
{
  const int dir = blockIdx.z;
  const int tm = blockIdx.x, tn = blockIdx.y;
  const float* __restrict__ w_ih = dir ? w_ih_b : w_ih_f;
  const float* __restrict__ bias = dir ? b_b : b_f;
  __shared__ float As[64][65];   // +1 pad -> 2-way max bank aliasing (free)
  __shared__ float Bs[64][65];
  __shared__ int sidx[64];
  const int tid = threadIdx.x;
  if (tid < 64) {
    const int s = tm * 64 + tid;
    const int tpos = dir ? (SEQ - 1 - s) : s;
    sidx[tid] = sent[tpos];
  }
  __syncthreads();
  float acc[4][4] = {};
  const int tr = tid >> 4, tc = tid & 15;
  for (int k0 = 0; k0 < EMB; k0 += 64) {
    #pragma unroll
    for (int i = 0; i < 4; ++i) {
      const int v = tid + i * 256;           // 1024 float4 slots: 64 rows x 16
      const int r = v >> 4, kv = v & 15;
      const float4 a4 = *reinterpret_cast<const float4*>(
          &embed[(size_t)sidx[r] * EMB + k0 + kv * 4]);
      As[r][kv*4+0] = a4.x; As[r][kv*4+1] = a4.y;
      As[r][kv*4+2] = a4.z; As[r][kv*4+3] = a4.w;
      const float4 b4 = *reinterpret_cast<const float4*>(
          &w_ih[(size_t)(tn * 64 + r) * EMB + k0 + kv * 4]);
      Bs[r][kv*4+0] = b4.x; Bs[r][kv*4+1] = b4.y;
      Bs[r][kv*4+2] = b4.z; Bs[r][kv*4+3] = b4.w;
    }
    __syncthreads();
    #pragma unroll
    for (int kk = 0; kk < 64; ++kk) {
      float a[4], b[4];
      #pragma unroll
      for (int i = 0; i < 4; ++i) a[i] = As[tr + 16 * i][kk];
      #pragma unroll
      for (int jj = 0; jj < 4; ++jj) b[jj] = Bs[tc + 16 * jj][kk];
      #pragma unroll
      for (int i = 0; i < 4; ++i)
        #pragma unroll
        for (int jj = 0; jj < 4; ++jj)
          acc[i][jj] = fmaf(a[i], b[jj], acc[i][jj]);
    }
    __syncthreads();
  }
  #pragma unroll
  for (int i = 0; i < 4; ++i) {
    const int srow = tm * 64 + tr + 16 * i;
    #pragma unroll
    for (int jj = 0; jj < 4; ++jj) {
      const int j = tn * 64 + tc + 16 * jj;   // tc fastest -> coalesced stores
      px[((size_t)dir * SEQ + srow) * GATE + j] = acc[i][jj] + bias[j];
    }
  }
}

// ---------------------------------------------------------------------------
// Kernel 2: LSTM recurrence -- ONE CU PER DIRECTION, zero cross-CU sync.
// R4-R7 post-mortem: every publish/poll protocol variant (LLC, L2, dual
// publish, 8 vs 16 blocks) cost an invariant ~5300-5900 cyc/step -- the
// global-memory handshake itself is the floor. Fix: make W_hh CU-resident.
// fp32 (1 MB) > register file (~512 KB, R1), but fp16 (512 KB) fits split:
//   - thread u = tid owns ALL FOUR gate rows of hidden unit u;
//   - gates i,f,g: 3 x 128 packed-half2 dwords = 384 VGPRs (asm-pinned,
//     R3 lesson: otherwise the scheduler sinks the loads into the t-loop);
//   - gate o: 128 KB in LDS, layout ow[m4][tid] (uint4) -> lanes stride
//     16 B, clean 32-bank sweep, ds_read_b128;
//   - h: 256 fp16 in LDS (512 B), double-buffered; chunk reads are
//     wave-uniform -> broadcast, conflict-free.
// v_dot2_f32_f16: 2 MACs/instr, fp32 accumulate. Gates add exact fp32 px;
// c/activations/h-output all fp32 -- only matvec operands are fp16
// (rel err ~5e-4; score threshold 108; R1 precedent: absmax 25 passed).
// Per step: VALU 512 dot2 (1024 cyc) + LDS o-stream 128 KB (1024 cyc,
// separate pipe) + activation + ONE __syncthreads => ~1400-1900 cyc,
// vs ~5500 for any cross-CU protocol. No reduction: each thread computes
// its unit's full dot products, updates its own c, writes its own h.
// ---------------------------------------------------------------------------
__global__ __attribute__((amdgpu_flat_work_group_size(256, 256),
                          amdgpu_waves_per_eu(1, 1)))
void lstm_1cu(
    const float* __restrict__ px, const float* __restrict__ w_hh_f,
    const float* __restrict__ w_hh_b, const float* __restrict__ h0,
    const float* __restrict__ c0, float* __restrict__ hs)
{
  const int dir = blockIdx.x;
  const int u = threadIdx.x;                 // hidden unit, 0..255
  const float* __restrict__ w_hh = dir ? w_hh_b : w_hh_f;

  __shared__ uint4 ow[32][256];                         // o-gate fp16: 128 KB
  __shared__ __align__(16) unsigned short hbs[2][256];  // h fp16 dbuf: 1 KB

  // --- load + pack weights (once) ---
  unsigned int wi[128], wf[128], wg[128];
  {
    const float* __restrict__ ri = &w_hh[(size_t)u * HID];
    const float* __restrict__ rf = ri + (size_t)256 * HID;
    const float* __restrict__ rg = ri + (size_t)512 * HID;
    const float* __restrict__ ro = ri + (size_t)768 * HID;
    #pragma unroll
    for (int m = 0; m < 64; ++m) {
      const float4 a = *reinterpret_cast<const float4*>(&ri[4 * m]);
      wi[2*m]   = packh2(a.x, a.y);
      wi[2*m+1] = packh2(a.z, a.w);
      const float4 b = *reinterpret_cast<const float4*>(&rf[4 * m]);
      wf[2*m]   = packh2(b.x, b.y);
      wf[2*m+1] = packh2(b.z, b.w);
      const float4 g = *reinterpret_cast<const float4*>(&rg[4 * m]);
      wg[2*m]   = packh2(g.x, g.y);
      wg[2*m+1] = packh2(g.z, g.w);
    }
    #pragma unroll
    for (int m4 = 0; m4 < 32; ++m4) {
      const float4 a = *reinterpret_cast<const float4*>(&ro[8 * m4]);
      const float4 b = *reinterpret_cast<const float4*>(&ro[8 * m4 + 4]);
      ow[m4][u] = make_uint4(packh2(a.x, a.y), packh2(a.z, a.w),
                             packh2(b.x, b.y), packh2(b.z, b.w));
    }
  }
  // Pin the 384 packed weights in arch VGPRs (definition point = here;
  // loads cannot sink/remat into the t-loop).
  #pragma unroll
  for (int m = 0; m < 128; m += 16) {
    asm volatile("" :
      "+v"(wi[m]),   "+v"(wi[m+1]), "+v"(wi[m+2]), "+v"(wi[m+3]),
      "+v"(wi[m+4]), "+v"(wi[m+5]), "+v"(wi[m+6]), "+v"(wi[m+7]),
      "+v"(wi[m+8]), "+v"(wi[m+9]), "+v"(wi[m+10]),"+v"(wi[m+11]),
      "+v"(wi[m+12]),"+v"(wi[m+13]),"+v"(wi[m+14]),"+v"(wi[m+15]));
    asm volatile("" :
      "+v"(wf[m]),   "+v"(wf[m+1]), "+v"(wf[m+2]), "+v"(wf[m+3]),
      "+v"(wf[m+4]), "+v"(wf[m+5]), "+v"(wf[m+6]), "+v"(wf[m+7]),
      "+v"(wf[m+8]), "+v"(wf[m+9]), "+v"(wf[m+10]),"+v"(wf[m+11]),
      "+v"(wf[m+12]),"+v"(wf[m+13]),"+v"(wf[m+14]),"+v"(wf[m+15]));
    asm volatile("" :
      "+v"(wg[m]),   "+v"(wg[m+1]), "+v"(wg[m+2]), "+v"(wg[m+3]),
      "+v"(wg[m+4]), "+v"(wg[m+5]), "+v"(wg[m+6]), "+v"(wg[m+7]),
      "+v"(wg[m+8]), "+v"(wg[m+9]), "+v"(wg[m+10]),"+v"(wg[m+11]),
      "+v"(wg[m+12]),"+v"(wg[m+13]),"+v"(wg[m+14]),"+v"(wg[m+15]));
  }

  // --- init state ---
  float c = c0[dir * HID + u];
  hbs[0][u] = __builtin_bit_cast(unsigned short, (_Float16)h0[dir * HID + u]);
  __syncthreads();

  const size_t pxbase = (size_t)dir * SEQ * GATE;
  float pi = px[pxbase + u];
  float pf = px[pxbase + 256 + u];
  float pg = px[pxbase + 512 + u];
  float po = px[pxbase + 768 + u];

  for (int t = 0; t < SEQ; ++t) {
    // prefetch next step's px behind the dot2 phase (coalesced across u)
    float ni = 0.f, nf = 0.f, ng = 0.f, no = 0.f;
    if (t + 1 < SEQ) {
      const size_t nb = pxbase + (size_t)(t + 1) * GATE;
      ni = px[nb + u];        nf = px[nb + 256 + u];
      ng = px[nb + 512 + u];  no = px[nb + 768 + u];
    }

    const uint4* __restrict__ hcur =
        reinterpret_cast<const uint4*>(&hbs[t & 1][0]);
    float si = 0.f, sf = 0.f, sg = 0.f, so = 0.f;
    #pragma unroll
    for (int m4 = 0; m4 < 32; ++m4) {
      const uint4 h4 = hcur[m4];          // broadcast (wave-uniform addr)
      const uint4 o4 = ow[m4][u];         // 16B-stride sweep, conflict-free
      si = dot2(h4.x, wi[4*m4  ], si);
      si = dot2(h4.y, wi[4*m4+1], si);
      si = dot2(h4.z, wi[4*m4+2], si);
      si = dot2(h4.w, wi[4*m4+3], si);
      sf = dot2(h4.x, wf[4*m4  ], sf);
      sf = dot2(h4.y, wf[4*m4+1], sf);
      sf = dot2(h4.z, wf[4*m4+2], sf);
      sf = dot2(h4.w, wf[4*m4+3], sf);
      sg = dot2(h4.x, wg[4*m4  ], sg);
      sg = dot2(h4.y, wg[4*m4+1], sg);
      sg = dot2(h4.z, wg[4*m4+2], sg);
      sg = dot2(h4.w, wg[4*m4+3], sg);
      so = dot2(h4.x, o4.x, so);
      so = dot2(h4.y, o4.y, so);
      so = dot2(h4.z, o4.z, so);
      so = dot2(h4.w, o4.w, so);
    }

    const float gi = si + pi, gf = sf + pf, gg = sg + pg, go = so + po;
    const float ai = 1.0f / (1.0f + expf(-gi));
    const float af = 1.0f / (1.0f + expf(-gf));
    const float ao = 1.0f / (1.0f + expf(-go));
    c = af * c + ai * tanhf(gg);
    const float hn = ao * tanhf(c);

    hs[((size_t)dir * SEQ + t) * HID + u] = hn;      // fp32 for feats kernel
    hbs[(t & 1) ^ 1][u] =
        __builtin_bit_cast(unsigned short, (_Float16)hn);
    pi = ni; pf = nf; pg = ng; po = no;
    __syncthreads();   // next step reads the buffer just written
  }
}

// ---------------------------------------------------------------------------
// Kernel 3: feats[t][j] = concat(h_fwd[t], h_bwd[S-1-t]) . w_tag[j] + b_tag[j]
// ---------------------------------------------------------------------------
__global__ __launch_bounds__(256) void feats_kernel(
    const float* __restrict__ hs, const float* __restrict__ w_tag,
    const float* __restrict__ b_tag, float* __restrict__ feats)
{
  const int t = blockIdx.x;
  const int tid = threadIdx.x;
  const int j = tid >> 3, p = tid & 7;
  const float* __restrict__ src = (p < 4)
      ? (hs + (size_t)t * HID + p * 64)                              // fwd half
      : (hs + (size_t)(SEQ + (SEQ - 1 - t)) * HID + (p - 4) * 64);   // bwd half
  const float* __restrict__ wt = w_tag + (size_t)j * (2 * HID) + p * 64;
  float sum = 0.f;
  #pragma unroll
  for (int k = 0; k < 64; k += 4) {
    const float4 x4 = *reinterpret_cast<const float4*>(&src[k]);
    const float4 w4 = *reinterpret_cast<const float4*>(&wt[k]);
    sum = fmaf(x4.x, w4.x, sum); sum = fmaf(x4.y, w4.y, sum);
    sum = fmaf(x4.z, w4.z, sum); sum = fmaf(x4.w, w4.w, sum);
  }
  sum += __shfl_down(sum, 4, 8);
  sum += __shfl_down(sum, 2, 8);
  sum += __shfl_down(sum, 1, 8);
  if (p == 0) feats[(size_t)t * NTAG + j] = sum + b_tag[j];
}

// ---------------------------------------------------------------------------
// Kernel 4: Viterbi + backtrace, single wave. Tie-breaking matches
// jnp.argmax (first index): strict '>' updates, lower half wins ties.
// ---------------------------------------------------------------------------
__global__ __launch_bounds__(64) void viterbi_kernel(
    const float* __restrict__ feats, const float* __restrict__ trans,
    float* __restrict__ out)
{
  __shared__ unsigned char bp[SEQ][NTAG];   // 64 KiB exactly
  const int lane = threadIdx.x;
  const int j = lane & 31, half = lane >> 5;
  float tr[16];
  #pragma unroll
  for (int qq = 0; qq < 16; ++qq) tr[qq] = trans[j * NTAG + half * 16 + qq];
  float fv = (j == 30) ? 0.0f : FNEG;       // START = 30
  float fcur = feats[j];
  for (int t = 0; t < SEQ; ++t) {
    const int tn = (t + 1 < SEQ) ? (t + 1) : (SEQ - 1);
    const float fnext = feats[(size_t)tn * NTAG + j];
    float best = -3.0e38f; int barg = 0;
    #pragma unroll
    for (int qq = 0; qq < 16; ++qq) {
      const int p = half * 16 + qq;
      const float sc = __shfl(fv, p) + tr[qq];
      if (sc > best) { best = sc; barg = p; }
    }
    const float ob = __shfl_down(best, 32);
    const int   oa = __shfl_down(barg, 32);
    float fvnew = 0.f;
    if (half == 0) {
      if (ob > best) { best = ob; barg = oa; }
      bp[t][j] = (unsigned char)barg;
      fvnew = best + fcur;
    }
    fv = __shfl(fvnew, j);   // broadcast updated fv[j] to both halves
    fcur = fnext;
  }
  float term = fv + trans[31 * NTAG + j];   // STOP = 31
  int idx = j;
  #pragma unroll
  for (int off = 16; off >= 1; off >>= 1) {
    const float ov = __shfl_down(term, off, 32);
    const int   oi = __shfl_down(idx, off, 32);
    if (ov > term) { term = ov; idx = oi; }
  }
  if (lane == 0) {
    out[0] = term;                 // path score
    int tag = idx;
    for (int t = SEQ - 1; t >= 0; --t) {
      out[1 + t] = (float)tag;     // y[S-1] = best_last; y[t] = bp[t+1][y[t+1]]
      tag = bp[t][tag];
    }
  }
}

// ---------------------------------------------------------------------------
extern "C" void kernel_launch(void* const* d_in, const int* in_sizes, int n_in,
                              void* d_out, int out_size, void* d_ws, size_t ws_size,
                              hipStream_t stream)
{
  (void)in_sizes; (void)n_in; (void)out_size; (void)ws_size;
  const int*   sent   = (const int*)  d_in[0];
  const float* embed  = (const float*)d_in[1];
  const float* w_ih_f = (const float*)d_in[2];
  const float* w_hh_f = (const float*)d_in[3];
  const float* b_f    = (const float*)d_in[4];
  const float* w_ih_b = (const float*)d_in[5];
  const float* w_hh_b = (const float*)d_in[6];
  const float* b_b    = (const float*)d_in[7];
  const float* w_tag  = (const float*)d_in[8];
  const float* b_tag  = (const float*)d_in[9];
  const float* trans  = (const float*)d_in[10];
  const float* h0     = (const float*)d_in[11];
  const float* c0     = (const float*)d_in[12];
  float* out = (float*)d_out;

  // ws: px[2][S][1024] f32 (16 MB) | hs[2][S][256] f32 (4 MB) | feats[S][32]
  float* px    = (float*)d_ws;
  float* hsbuf = px + (size_t)2 * SEQ * GATE;
  float* feats = hsbuf + (size_t)2 * SEQ * HID;

  dim3 gemm_grid(SEQ / 64, GATE / 64, 2);
  px_gemm<<<gemm_grid, 256, 0, stream>>>(sent, embed, w_ih_f, b_f,
                                         w_ih_b, b_b, px);
  lstm_1cu<<<2, 256, 0, stream>>>(px, w_hh_f, w_hh_b, h0, c0, hsbuf);
  feats_kernel<<<SEQ, 256, 0, stream>>>(hsbuf, w_tag, b_tag, feats);
  viterbi_kernel<<<1, 64, 0, stream>>>(feats, trans, out);
}